// Round 1
// baseline (705.861 us; speedup 1.0000x reference)
//
#include <hip/hip_runtime.h>
#include <hip/hip_bf16.h>

// VectorQuantizer: z [8,64,64,64] fp32 (BCHW), embedding [8192,64] fp32.
// Outputs (concat): z_q [8,64,64,64] fp32 (BCHW), indices [32768] written as fp32.
//
// d = ||zn||^2 + ||e||^2 - 2 zn.e ; ||zn||^2 is constant per pixel -> argmin over
// (se[n] - 2*dot) matches the reference argmin.

#define NPIX 32768
#define NE   8192
#define EDIM 64
#define HW   4096          // 64*64
#define NGRP 8
#define CODES_PER_GRP (NE / NGRP)   // 1024

// ---------------- K1: normalize codebook, store se = sum(e_norm^2) -------------
__global__ __launch_bounds__(256) void k_norm_emb(const float* __restrict__ emb,
                                                  float* __restrict__ e_norm,
                                                  float* __restrict__ se) {
    const int wave = threadIdx.x >> 6;        // 4 waves/block, 1 code per wave
    const int lane = threadIdx.x & 63;
    const int n = blockIdx.x * 4 + wave;      // 0..8191
    float v = emb[n * EDIM + lane];
    float ss = v * v;
    #pragma unroll
    for (int off = 32; off; off >>= 1) ss += __shfl_xor(ss, off, 64);
    const float inv = 1.0f / fmaxf(sqrtf(ss), 1e-12f);
    const float en = v * inv;
    e_norm[n * EDIM + lane] = en;
    float s2 = en * en;
    #pragma unroll
    for (int off = 32; off; off >>= 1) s2 += __shfl_xor(s2, off, 64);
    if (lane == 0) se[n] = s2;
}

// ---------------- K2: per-pixel partial argmin over one code group -------------
__global__ __launch_bounds__(256) void k_vq_partial(const float* __restrict__ z,
                                                    const float* __restrict__ e_norm,
                                                    const float* __restrict__ se,
                                                    float* __restrict__ part_val,
                                                    int*   __restrict__ part_idx) {
    const int p = blockIdx.x * 256 + threadIdx.x;   // pixel 0..32767
    const int g = blockIdx.y;                       // code group 0..7
    const int b  = p >> 12;                         // p / 4096
    const int hw = p & (HW - 1);

    // Load this pixel's channel vector (coalesced across lanes for each c) and
    // L2-normalize it.
    const float* zp = z + b * (EDIM * HW) + hw;
    float zr[EDIM];
    float ss = 0.0f;
    #pragma unroll
    for (int c = 0; c < EDIM; ++c) {
        const float v = zp[c * HW];
        zr[c] = v;
        ss += v * v;
    }
    const float inv = 1.0f / fmaxf(sqrtf(ss), 1e-12f);
    #pragma unroll
    for (int c = 0; c < EDIM; ++c) zr[c] *= inv;

    // Stream this group's codes; addresses are wave-uniform -> scalar loads.
    const float4* __restrict__ e4 = (const float4*)e_norm;
    float best = 3.0e38f;
    int bidx = 0;
    const int n0 = g * CODES_PER_GRP;
    for (int n = n0; n < n0 + CODES_PER_GRP; ++n) {
        float a0 = 0.0f, a1 = 0.0f, a2 = 0.0f, a3 = 0.0f;
        #pragma unroll
        for (int c4 = 0; c4 < EDIM / 4; c4 += 4) {
            const float4 e0 = e4[n * (EDIM / 4) + c4 + 0];
            const float4 e1 = e4[n * (EDIM / 4) + c4 + 1];
            const float4 e2 = e4[n * (EDIM / 4) + c4 + 2];
            const float4 e3 = e4[n * (EDIM / 4) + c4 + 3];
            const int c = c4 * 4;
            a0 = fmaf(zr[c +  0], e0.x, a0); a0 = fmaf(zr[c +  1], e0.y, a0);
            a0 = fmaf(zr[c +  2], e0.z, a0); a0 = fmaf(zr[c +  3], e0.w, a0);
            a1 = fmaf(zr[c +  4], e1.x, a1); a1 = fmaf(zr[c +  5], e1.y, a1);
            a1 = fmaf(zr[c +  6], e1.z, a1); a1 = fmaf(zr[c +  7], e1.w, a1);
            a2 = fmaf(zr[c +  8], e2.x, a2); a2 = fmaf(zr[c +  9], e2.y, a2);
            a2 = fmaf(zr[c + 10], e2.z, a2); a2 = fmaf(zr[c + 11], e2.w, a2);
            a3 = fmaf(zr[c + 12], e3.x, a3); a3 = fmaf(zr[c + 13], e3.y, a3);
            a3 = fmaf(zr[c + 14], e3.z, a3); a3 = fmaf(zr[c + 15], e3.w, a3);
        }
        const float dot = (a0 + a1) + (a2 + a3);
        const float dist = fmaf(-2.0f, dot, se[n]);
        // strict < with ascending n keeps the smallest index on exact ties
        if (dist < best) { best = dist; bidx = n; }
    }
    part_val[g * NPIX + p] = best;
    part_idx[g * NPIX + p] = bidx;
}

// ---------------- K3: reduce groups, gather code, write outputs ----------------
__global__ __launch_bounds__(256) void k_finalize(const float* __restrict__ part_val,
                                                  const int*   __restrict__ part_idx,
                                                  const float* __restrict__ e_norm,
                                                  float* __restrict__ out) {
    const int p = blockIdx.x * 256 + threadIdx.x;
    float best = 3.0e38f;
    int bidx = 0;
    #pragma unroll
    for (int g = 0; g < NGRP; ++g) {
        const float v = part_val[g * NPIX + p];
        const int   i = part_idx[g * NPIX + p];
        // ascending group order + strict < -> smallest index wins exact ties
        if (v < best) { best = v; bidx = i; }
    }
    out[NPIX * EDIM + p] = (float)bidx;   // indices block, as float values

    const int b  = p >> 12;
    const int hw = p & (HW - 1);
    float* op = out + b * (EDIM * HW) + hw;
    const float* ep = e_norm + bidx * EDIM;
    #pragma unroll
    for (int c = 0; c < EDIM; ++c) op[c * HW] = ep[c];   // coalesced per c
}

extern "C" void kernel_launch(void* const* d_in, const int* in_sizes, int n_in,
                              void* d_out, int out_size, void* d_ws, size_t ws_size,
                              hipStream_t stream) {
    const float* z   = (const float*)d_in[0];   // 2,097,152 fp32
    const float* emb = (const float*)d_in[1];   // 524,288 fp32
    float* out = (float*)d_out;                 // 2,129,920 fp32

    // workspace layout (fp32 elements)
    float* e_norm   = (float*)d_ws;                          // 524,288
    float* se       = e_norm + NE * EDIM;                    // 8,192
    float* part_val = se + NE;                               // 262,144
    int*   part_idx = (int*)(part_val + NGRP * NPIX);        // 262,144

    k_norm_emb<<<NE / 4, 256, 0, stream>>>(emb, e_norm, se);
    k_vq_partial<<<dim3(NPIX / 256, NGRP), 256, 0, stream>>>(z, e_norm, se,
                                                             part_val, part_idx);
    k_finalize<<<NPIX / 256, 256, 0, stream>>>(part_val, part_idx, e_norm, out);
}

// Round 2
// 655.016 us; speedup vs baseline: 1.0776x; 1.0776x over previous
//
#include <hip/hip_runtime.h>
#include <hip/hip_bf16.h>

// VectorQuantizer: z [8,64,64,64] fp32 (BCHW), embedding [8192,64] fp32.
// Outputs (concat): z_q [8,64,64,64] fp32 (BCHW), indices [32768] as fp32.
//
// argmin_n ||zn - e_n||^2 == argmin_n ( se[n] - 2*dot(zn, e_n) )  (||zn||^2 const/pixel)

#define NPIX 32768
#define NE   8192
#define EDIM 64
#define HW   4096          // 64*64
#define NGRP 16
#define CODES_PER_GRP (NE / NGRP)   // 512

// ---------------- K0: init packed argmin keys --------------------------------
__global__ __launch_bounds__(256) void k_init(unsigned long long* __restrict__ packed) {
    packed[blockIdx.x * 256 + threadIdx.x] = ~0ull;
}

// ---------------- K1: normalize codebook, store se = sum(e_norm^2) -----------
__global__ __launch_bounds__(256) void k_norm_emb(const float* __restrict__ emb,
                                                  float* __restrict__ e_norm,
                                                  float* __restrict__ se) {
    const int wave = threadIdx.x >> 6;        // 4 waves/block, 1 code per wave
    const int lane = threadIdx.x & 63;
    const int n = blockIdx.x * 4 + wave;      // 0..8191
    float v = emb[n * EDIM + lane];
    float ss = v * v;
    #pragma unroll
    for (int off = 32; off; off >>= 1) ss += __shfl_xor(ss, off, 64);
    const float inv = 1.0f / fmaxf(sqrtf(ss), 1e-12f);
    const float en = v * inv;
    e_norm[n * EDIM + lane] = en;
    float s2 = en * en;
    #pragma unroll
    for (int off = 32; off; off >>= 1) s2 += __shfl_xor(s2, off, 64);
    if (lane == 0) se[n] = s2;
}

// map float to unsigned with same total order
__device__ __forceinline__ unsigned int order_u32(float f) {
    unsigned int s = __float_as_uint(f);
    return (s & 0x80000000u) ? ~s : (s | 0x80000000u);
}

// ---------------- K2: per-pixel partial argmin over one code group -----------
// __launch_bounds__(256, 4): 4 waves/EU min -> <=128 VGPR. zr[64] MUST stay in
// registers; the R1 default cap (VGPR_Count=56) spilled it and serialized the
// FMA chain (VALUBusy 41%).
__global__ __launch_bounds__(256, 4) void k_vq_partial(const float* __restrict__ z,
                                                       const float* __restrict__ e_norm,
                                                       const float* __restrict__ se,
                                                       unsigned long long* __restrict__ packed) {
    const int p = blockIdx.x * 256 + threadIdx.x;   // pixel 0..32767
    const int g = blockIdx.y;                       // code group 0..15
    const int b  = p >> 12;                         // p / 4096
    const int hw = p & (HW - 1);

    // Load this pixel's channel vector (coalesced across lanes for each c),
    // L2-normalize into registers.
    const float* zp = z + b * (EDIM * HW) + hw;
    float zr[EDIM];
    float ss = 0.0f;
    #pragma unroll
    for (int c = 0; c < EDIM; ++c) {
        const float v = zp[c * HW];
        zr[c] = v;
        ss += v * v;
    }
    const float inv = 1.0f / fmaxf(sqrtf(ss), 1e-12f);
    #pragma unroll
    for (int c = 0; c < EDIM; ++c) zr[c] *= inv;

    // Stream this group's codes; n is wave-uniform -> scalar (s_load) reads.
    const float4* __restrict__ e4 = (const float4*)e_norm;
    float best = 3.0e38f;
    int bidx = 0;
    const int n0 = g * CODES_PER_GRP;
    for (int n = n0; n < n0 + CODES_PER_GRP; ++n) {
        float a0 = 0.0f, a1 = 0.0f, a2 = 0.0f, a3 = 0.0f;
        #pragma unroll
        for (int c4 = 0; c4 < EDIM / 4; c4 += 4) {
            const float4 e0 = e4[n * (EDIM / 4) + c4 + 0];
            const float4 e1 = e4[n * (EDIM / 4) + c4 + 1];
            const float4 e2 = e4[n * (EDIM / 4) + c4 + 2];
            const float4 e3 = e4[n * (EDIM / 4) + c4 + 3];
            const int c = c4 * 4;
            a0 = fmaf(zr[c +  0], e0.x, a0); a0 = fmaf(zr[c +  1], e0.y, a0);
            a0 = fmaf(zr[c +  2], e0.z, a0); a0 = fmaf(zr[c +  3], e0.w, a0);
            a1 = fmaf(zr[c +  4], e1.x, a1); a1 = fmaf(zr[c +  5], e1.y, a1);
            a1 = fmaf(zr[c +  6], e1.z, a1); a1 = fmaf(zr[c +  7], e1.w, a1);
            a2 = fmaf(zr[c +  8], e2.x, a2); a2 = fmaf(zr[c +  9], e2.y, a2);
            a2 = fmaf(zr[c + 10], e2.z, a2); a2 = fmaf(zr[c + 11], e2.w, a2);
            a3 = fmaf(zr[c + 12], e3.x, a3); a3 = fmaf(zr[c + 13], e3.y, a3);
            a3 = fmaf(zr[c + 14], e3.z, a3); a3 = fmaf(zr[c + 15], e3.w, a3);
        }
        const float dot = (a0 + a1) + (a2 + a3);
        const float dist = fmaf(-2.0f, dot, se[n]);
        // strict < with ascending n keeps the smallest index on exact ties
        if (dist < best) { best = dist; bidx = n; }
    }
    // key = (order(dist) << 32) | idx ; u64 min == (min dist, tie -> min idx).
    const unsigned long long key =
        ((unsigned long long)order_u32(best) << 32) | (unsigned int)bidx;
    atomicMin(&packed[p], key);
}

// ---------------- K3: unpack winner, gather code, write outputs --------------
__global__ __launch_bounds__(256) void k_finalize(const unsigned long long* __restrict__ packed,
                                                  const float* __restrict__ e_norm,
                                                  float* __restrict__ out) {
    const int p = blockIdx.x * 256 + threadIdx.x;
    const int bidx = (int)(packed[p] & 0xFFFFFFFFull);
    out[NPIX * EDIM + p] = (float)bidx;   // indices block, as float values

    const int b  = p >> 12;
    const int hw = p & (HW - 1);
    float* op = out + b * (EDIM * HW) + hw;
    const float* ep = e_norm + bidx * EDIM;
    #pragma unroll
    for (int c = 0; c < EDIM; ++c) op[c * HW] = ep[c];   // coalesced per c
}

extern "C" void kernel_launch(void* const* d_in, const int* in_sizes, int n_in,
                              void* d_out, int out_size, void* d_ws, size_t ws_size,
                              hipStream_t stream) {
    const float* z   = (const float*)d_in[0];   // 2,097,152 fp32
    const float* emb = (const float*)d_in[1];   // 524,288 fp32
    float* out = (float*)d_out;                 // 2,129,920 fp32

    // workspace layout
    float* e_norm = (float*)d_ws;                               // 524,288 fp32 (2 MB)
    float* se     = e_norm + NE * EDIM;                         // 8,192 fp32
    unsigned long long* packed = (unsigned long long*)(se + NE);// 32,768 u64 (256 KB)

    k_init<<<NPIX / 256, 256, 0, stream>>>(packed);
    k_norm_emb<<<NE / 4, 256, 0, stream>>>(emb, e_norm, se);
    k_vq_partial<<<dim3(NPIX / 256, NGRP), 256, 0, stream>>>(z, e_norm, se, packed);
    k_finalize<<<NPIX / 256, 256, 0, stream>>>(packed, e_norm, out);
}